// Round 2
// baseline (236.392 us; speedup 1.0000x reference)
//
#include <hip/hip_runtime.h>

// SelfAttention (B=4, C=256, H=W=64): fused projections + flash attention.
// Design notes (round 2 resubmit — rounds 0/1 failed on container infra, incl. a
// stub kernel, so no counter evidence yet; static re-review done instead):
//  - No fp32 MFMA on CDNA4 -> bf16 hi/lo split, 3-term MFMA for projections and
//    QK^T (~fp32 accurate); plain bf16 for P,V in attn*V (error ~1e-3 abs).
//  - Flash-style: never materialize the [B,N,N] score tensor.
//  - All LDS tiles 16B-granule XOR-swizzled -> bank-balanced staging + frag reads.
//  - P aliases S in LDS (each softmax thread overwrites the granule it read).
//  - Static LDS kept at exactly 64KB for the flash kernel.
//  - NEW: XCD-aware block swizzle in k_flash so each XCD's L2 holds ~1 batch of
//    K/V (2.5MB < 4MB L2/XCD) instead of all 4 batches (10MB, thrash).

#define B_ 4
#define C_ 256
#define N_ 4096
#define CQK 32

typedef __attribute__((ext_vector_type(8))) short short8;
typedef __attribute__((ext_vector_type(16))) float f32x16;
typedef __attribute__((ext_vector_type(4))) float f32x4;

__device__ __forceinline__ unsigned short f2bf(float f) {
  unsigned int u = __builtin_bit_cast(unsigned int, f);
  u = (u + 0x7fffu + ((u >> 16) & 1u)) >> 16;  // RNE
  return (unsigned short)u;
}
__device__ __forceinline__ float bf2f(unsigned short s) {
  unsigned int u = ((unsigned int)s) << 16;
  return __builtin_bit_cast(float, u);
}
__device__ __forceinline__ f32x16 mfma16(short8 a, short8 b, f32x16 c) {
  return __builtin_amdgcn_mfma_f32_32x32x16_bf16(a, b, c, 0, 0, 0);
}
// swizzled element index into bf16 LDS tiles (16B granules XORed by row)
__device__ __forceinline__ int swz64(int row, int col) {  // rows of 64 bf16
  return row * 64 + ((((col >> 3) ^ row) & 7) << 3) + (col & 7);
}
__device__ __forceinline__ int swz32(int row, int col) {  // rows of 32 bf16
  return row * 32 + ((((col >> 3) ^ row) & 3) << 3) + (col & 7);
}

// ---------------- kernel 1: transpose + hi/lo split of x ----------------
// x [B][C][N] fp32  ->  xthi/xtlo [B][N][C] bf16
__global__ __launch_bounds__(256) void k_split_x(const float* __restrict__ x,
                                                 unsigned short* __restrict__ xthi,
                                                 unsigned short* __restrict__ xtlo) {
  __shared__ __align__(16) float tile[64 * 65];
  const int it = blockIdx.x, ct = blockIdx.y, b = blockIdx.z;
  const int i0 = it * 64, c0 = ct * 64;
  const int t = threadIdx.x;
  {
    const int i = t & 63, cb = t >> 6;
#pragma unroll
    for (int z = 0; z < 16; ++z) {
      const int c = z * 4 + cb;
      tile[i * 65 + c] = x[(b * C_ + c0 + c) * N_ + i0 + i];
    }
  }
  __syncthreads();
  {
    const int ii = t >> 2, p = t & 3;
    short8 h0, h1, l0, l1;
#pragma unroll
    for (int e = 0; e < 16; ++e) {
      const float f = tile[ii * 65 + p * 16 + e];
      const unsigned short hb = f2bf(f);
      const unsigned short lb = f2bf(f - bf2f(hb));
      if (e < 8) { h0[e] = (short)hb; l0[e] = (short)lb; }
      else       { h1[e - 8] = (short)hb; l1[e - 8] = (short)lb; }
    }
    const int base = (b * N_ + i0 + ii) * C_ + c0 + p * 16;
    *(short8*)(xthi + base) = h0;
    *(short8*)(xthi + base + 8) = h1;
    *(short8*)(xtlo + base) = l0;
    *(short8*)(xtlo + base + 8) = l1;
  }
}

// ---------------- kernel 2: hi/lo split of a weight matrix ----------------
__global__ void k_split_w(const float* __restrict__ src, unsigned short* __restrict__ hi,
                          unsigned short* __restrict__ lo, int n) {
  const int i = blockIdx.x * 256 + threadIdx.x;
  if (i < n) {
    const float f = src[i];
    const unsigned short h = f2bf(f);
    hi[i] = h;
    lo[i] = f2bf(f - bf2f(h));
  }
}

// ---------------- kernel 3: fused q/k/v projection GEMM ----------------
// C[o][i] = sum_c W[o][c] * x[c][i] + bias, o in [0,320) concat(q32,k32,v256)
// q,k written transposed: [B][N][32] hi/lo bf16; v written [B][C][N] bf16.
__global__ __launch_bounds__(256) void k_proj(
    const unsigned short* __restrict__ wqh, const unsigned short* __restrict__ wql,
    const unsigned short* __restrict__ wkh, const unsigned short* __restrict__ wkl,
    const unsigned short* __restrict__ wvh, const unsigned short* __restrict__ wvl,
    const unsigned short* __restrict__ xthi, const unsigned short* __restrict__ xtlo,
    const float* __restrict__ bq, const float* __restrict__ bk,
    const float* __restrict__ bv,
    unsigned short* __restrict__ qhg, unsigned short* __restrict__ qlg,
    unsigned short* __restrict__ khg, unsigned short* __restrict__ klg,
    unsigned short* __restrict__ vg) {
  __shared__ __align__(16) char sm[33792];
  unsigned short* awh = (unsigned short*)sm;       // [64][64] W hi (swizzled)
  unsigned short* awl = awh + 4096;
  unsigned short* bxh = awl + 4096;                // [64][64] x^T hi
  unsigned short* bxl = bxh + 4096;
  float* qt = (float*)sm;                          // epilogue reuse: [64][65] f32

  const int it = blockIdx.x, ot = blockIdx.y, b = blockIdx.z;
  const int i0 = it * 64, o0 = ot * 64;
  const int t = threadIdx.x, lane = t & 63, w = t >> 6, h = lane >> 5;
  const int mb = w >> 1, nb = w & 1;
  const int srow = t >> 2, sp = t & 3;

  const int og = o0 + srow;
  const unsigned short *wh, *wl;
  if (og < 32)      { wh = wqh + og * C_;        wl = wql + og * C_; }
  else if (og < 64) { wh = wkh + (og - 32) * C_; wl = wkl + (og - 32) * C_; }
  else              { wh = wvh + (og - 64) * C_; wl = wvl + (og - 64) * C_; }
  const unsigned short* xh = xthi + (b * N_ + i0 + srow) * C_;
  const unsigned short* xl = xtlo + (b * N_ + i0 + srow) * C_;

  f32x16 acc;
#pragma unroll
  for (int e = 0; e < 16; ++e) acc[e] = 0.f;
  const int m = 32 * mb + (lane & 31);
  const int n = 32 * nb + (lane & 31);

  for (int kt = 0; kt < 4; ++kt) {
    const int cb = kt * 64 + sp * 16;
    *(short8*)&awh[swz64(srow, sp * 16)]     = *(const short8*)(wh + cb);
    *(short8*)&awh[swz64(srow, sp * 16 + 8)] = *(const short8*)(wh + cb + 8);
    *(short8*)&awl[swz64(srow, sp * 16)]     = *(const short8*)(wl + cb);
    *(short8*)&awl[swz64(srow, sp * 16 + 8)] = *(const short8*)(wl + cb + 8);
    *(short8*)&bxh[swz64(srow, sp * 16)]     = *(const short8*)(xh + cb);
    *(short8*)&bxh[swz64(srow, sp * 16 + 8)] = *(const short8*)(xh + cb + 8);
    *(short8*)&bxl[swz64(srow, sp * 16)]     = *(const short8*)(xl + cb);
    *(short8*)&bxl[swz64(srow, sp * 16 + 8)] = *(const short8*)(xl + cb + 8);
    __syncthreads();
#pragma unroll
    for (int kk = 0; kk < 4; ++kk) {
      const int kb = kk * 16 + h * 8;
      const short8 ah  = *(const short8*)&awh[swz64(m, kb)];
      const short8 al2 = *(const short8*)&awl[swz64(m, kb)];
      const short8 bh  = *(const short8*)&bxh[swz64(n, kb)];
      const short8 bl2 = *(const short8*)&bxl[swz64(n, kb)];
      acc = mfma16(ah, bh, acc);   // hi*hi
      acc = mfma16(ah, bl2, acc);  // hi*lo
      acc = mfma16(al2, bh, acc);  // lo*hi
    }
    __syncthreads();
  }

  if (ot > 0) {  // v epilogue: direct [B][C][N] bf16 store
#pragma unroll
    for (int e = 0; e < 16; ++e) {
      const int r = 32 * mb + (e & 3) + 8 * (e >> 2) + 4 * h;
      const int oc = o0 - 64 + r;
      vg[(b * C_ + oc) * N_ + i0 + n] = f2bf(acc[e] + bv[oc]);
    }
  } else {  // q/k epilogue: LDS transpose -> [B][N][32] hi/lo
#pragma unroll
    for (int e = 0; e < 16; ++e) {
      const int r = 32 * mb + (e & 3) + 8 * (e >> 2) + 4 * h;
      const float bias = (r < 32) ? bq[r] : bk[r - 32];
      qt[r * 65 + n] = acc[e] + bias;
    }
    __syncthreads();
    const int ii = t >> 2;
    short8 hv0, hv1, lv0, lv1;
#pragma unroll
    for (int e = 0; e < 16; ++e) {
      const float f = qt[(sp * 16 + e) * 65 + ii];
      const unsigned short hb = f2bf(f);
      const unsigned short lb = f2bf(f - bf2f(hb));
      if (e < 8) { hv0[e] = (short)hb; lv0[e] = (short)lb; }
      else       { hv1[e - 8] = (short)hb; lv1[e - 8] = (short)lb; }
    }
    if (sp < 2) {
      const int base = (b * N_ + i0 + ii) * CQK + sp * 16;
      *(short8*)(qhg + base) = hv0; *(short8*)(qhg + base + 8) = hv1;
      *(short8*)(qlg + base) = lv0; *(short8*)(qlg + base + 8) = lv1;
    } else {
      const int base = (b * N_ + i0 + ii) * CQK + sp * 16 - 32;
      *(short8*)(khg + base) = hv0; *(short8*)(khg + base + 8) = hv1;
      *(short8*)(klg + base) = lv0; *(short8*)(klg + base + 8) = lv1;
    }
  }
}

// ---------------- kernel 4: flash attention + residual ----------------
// 512 threads, Qtile=64, Ktile=64. Wave w owns channels c in [32w,32w+32),
// acc0/acc1 = O tiles for i in [0,32)/[32,64). S via 3-term hi/lo MFMA.
__global__ __launch_bounds__(512, 2) void k_flash(
    const unsigned short* __restrict__ qhg, const unsigned short* __restrict__ qlg,
    const unsigned short* __restrict__ khg, const unsigned short* __restrict__ klg,
    const unsigned short* __restrict__ vg, const float* __restrict__ x,
    const float* __restrict__ gamma, float* __restrict__ out) {
  __shared__ __align__(16) char sm[65536];
  unsigned short* kh = (unsigned short*)sm;           // [64][32] (Q-hi staging first)
  unsigned short* kl = (unsigned short*)(sm + 4096);  // [64][32] (Q-lo staging first)
  unsigned short* vt = (unsigned short*)(sm + 8192);  // [256][64]
  float* stf = (float*)(sm + 40960);                  // [64][64] f32 swizzled; P aliases
  char* stb = sm + 40960;
  float* alphaf = (float*)(sm + 57344);               // [64]
  float* otf = (float*)sm;                            // epilogue [256][64] swizzled

  // XCD-aware swizzle: round-robin dispatch (blk%8 = XCD) => batch b lives on
  // XCDs {2b, 2b+1}; per-XCD K/V working set = 1 batch (~2.5MB < 4MB L2).
  const int blk = blockIdx.x;
  const int b = (blk >> 1) & 3;
  const int qt_ = (blk >> 3) * 2 + (blk & 1);
  const int q0 = qt_ * 64;
  const int t = threadIdx.x, lane = t & 63, w = t >> 6, h = lane >> 5;
  const int l31 = lane & 31;
  const int r_sm = t >> 3, p_sm = t & 7;

  // stage Q tile (hi into kh region, lo into kl region)
  {
    const int r = (t & 255) >> 2, g = t & 3;
    const unsigned short* src = ((t < 256) ? qhg : qlg) + (b * N_ + q0 + r) * CQK + g * 8;
    unsigned short* dst = (t < 256) ? kh : kl;
    *(short8*)&dst[swz32(r, g * 8)] = *(const short8*)src;
  }
  __syncthreads();
  // preload Q fragments (used by waves 0..3 for S)
  const int mbs = (w >> 1) & 1, nbs = w & 1;
  short8 qfh[2], qfl[2];
  {
    const int mq = 32 * mbs + l31;
#pragma unroll
    for (int kk = 0; kk < 2; ++kk) {
      qfh[kk] = *(const short8*)&kh[swz32(mq, kk * 16 + h * 8)];
      qfl[kk] = *(const short8*)&kl[swz32(mq, kk * 16 + h * 8)];
    }
  }
  __syncthreads();  // Q region becomes K staging below

  f32x16 acc0, acc1;
#pragma unroll
  for (int e = 0; e < 16; ++e) { acc0[e] = 0.f; acc1[e] = 0.f; }
  float m_run = -1e30f, l_run = 0.f;
  const float gm = gamma[0];

  for (int kt = 0; kt < 64; ++kt) {
    const int j0 = kt * 64;
    {  // stage K hi/lo
      const int r = (t & 255) >> 2, g = t & 3;
      const unsigned short* src = ((t < 256) ? khg : klg) + (b * N_ + j0 + r) * CQK + g * 8;
      unsigned short* dst = (t < 256) ? kh : kl;
      *(short8*)&dst[swz32(r, g * 8)] = *(const short8*)src;
    }
#pragma unroll
    for (int pass = 0; pass < 4; ++pass) {  // stage V [256][64]
      const int gid = pass * 512 + t;
      const int c = gid >> 3, g = gid & 7;
      *(short8*)&vt[swz64(c, g * 8)] =
          *(const short8*)(vg + (b * C_ + c) * N_ + j0 + g * 8);
    }
    __syncthreads();
    // S = Q K^T (waves 0..3), fp32, written swizzled to stf
    if (w < 4) {
      f32x16 sa;
#pragma unroll
      for (int e = 0; e < 16; ++e) sa[e] = 0.f;
      const int jn = 32 * nbs + l31;
#pragma unroll
      for (int kk = 0; kk < 2; ++kk) {
        const short8 bh = *(const short8*)&kh[swz32(jn, kk * 16 + h * 8)];
        const short8 bl = *(const short8*)&kl[swz32(jn, kk * 16 + h * 8)];
        sa = mfma16(qfh[kk], bh, sa);
        sa = mfma16(qfh[kk], bl, sa);
        sa = mfma16(qfl[kk], bh, sa);
      }
#pragma unroll
      for (int e = 0; e < 16; ++e) {
        const int ri = 32 * mbs + (e & 3) + 8 * (e >> 2) + 4 * h;
        stf[ri * 64 + ((((jn >> 2) ^ ri) & 15) << 2) + (jn & 3)] = sa[e];
      }
    }
    __syncthreads();
    // online softmax: thread (r_sm,p_sm) owns cols [8p,8p+8) of row r_sm
    {
      float* p0 = stf + r_sm * 64 + ((((2 * p_sm) ^ r_sm) & 15) << 2);
      float* p1 = stf + r_sm * 64 + ((((2 * p_sm + 1) ^ r_sm) & 15) << 2);
      const f32x4 a0 = *(const f32x4*)p0;
      const f32x4 a1 = *(const f32x4*)p1;
      float s[8];
#pragma unroll
      for (int e = 0; e < 4; ++e) { s[e] = a0[e]; s[4 + e] = a1[e]; }
      float mx = s[0];
#pragma unroll
      for (int e = 1; e < 8; ++e) mx = fmaxf(mx, s[e]);
      mx = fmaxf(mx, __shfl_xor(mx, 1));
      mx = fmaxf(mx, __shfl_xor(mx, 2));
      mx = fmaxf(mx, __shfl_xor(mx, 4));
      const float mnew = fmaxf(m_run, mx);
      const float al = __expf(m_run - mnew);
      float ts = 0.f;
      short8 pv8;
#pragma unroll
      for (int e = 0; e < 8; ++e) {
        const float pe = __expf(s[e] - mnew);
        ts += pe;
        pv8[e] = (short)f2bf(pe);
      }
      ts += __shfl_xor(ts, 1);
      ts += __shfl_xor(ts, 2);
      ts += __shfl_xor(ts, 4);
      l_run = l_run * al + ts;
      m_run = mnew;
      *(short8*)p0 = pv8;  // P (bf16) overwrites the granule this thread read
      if (p_sm == 0) alphaf[r_sm] = al;
    }
    __syncthreads();
    // rescale O by alpha[row]
#pragma unroll
    for (int eq = 0; eq < 4; ++eq) {
      const f32x4 av0 = *(const f32x4*)&alphaf[4 * h + 8 * eq];
      const f32x4 av1 = *(const f32x4*)&alphaf[32 + 4 * h + 8 * eq];
#pragma unroll
      for (int q = 0; q < 4; ++q) {
        acc0[4 * eq + q] *= av0[q];
        acc1[4 * eq + q] *= av1[q];
      }
    }
    // O += P * V^T
    {
      const int crow = 32 * w + l31;
#pragma unroll
      for (int kk = 0; kk < 4; ++kk) {
        const int g0 = ((4 * kk + 2 * h) ^ l31) & 15;  // P col-granule swizzle
        const short8 pa0 = *(const short8*)(stb + l31 * 256 + (g0 << 4));
        const short8 pa1 = *(const short8*)(stb + (32 + l31) * 256 + (g0 << 4));
        const short8 vf = *(const short8*)&vt[swz64(crow, kk * 16 + h * 8)];
        acc0 = mfma16(pa0, vf, acc0);
        acc1 = mfma16(pa1, vf, acc1);
      }
    }
    __syncthreads();
  }

  // finalize: O /= l, transpose through LDS, out = gamma*O + x
  if (p_sm == 0) alphaf[r_sm] = 1.0f / l_run;
  __syncthreads();
#pragma unroll
  for (int eq = 0; eq < 4; ++eq) {
    const f32x4 av0 = *(const f32x4*)&alphaf[4 * h + 8 * eq];
    const f32x4 av1 = *(const f32x4*)&alphaf[32 + 4 * h + 8 * eq];
#pragma unroll
    for (int q = 0; q < 4; ++q) {
      acc0[4 * eq + q] *= av0[q];
      acc1[4 * eq + q] *= av1[q];
    }
  }
  __syncthreads();  // alphaf reads done before otf (spans full 64KB) overwrites
  {
    const int cc = 32 * w + l31;
#pragma unroll
    for (int e = 0; e < 16; ++e) {
      const int r0 = (e & 3) + 8 * (e >> 2) + 4 * h;
      otf[cc * 64 + ((((r0 >> 2) ^ cc) & 15) << 2) + (r0 & 3)] = acc0[e];
      const int r1 = 32 + r0;
      otf[cc * 64 + ((((r1 >> 2) ^ cc) & 15) << 2) + (r1 & 3)] = acc1[e];
    }
  }
  __syncthreads();
#pragma unroll
  for (int pass = 0; pass < 8; ++pass) {
    const int idx = pass * 512 + t;
    const int c = idx >> 4, gi = idx & 15;
    const f32x4 ov = *(const f32x4*)(otf + c * 64 + (((gi ^ c) & 15) << 2));
    const int gbase = (b * C_ + c) * N_ + q0 + gi * 4;
    const f32x4 xv = *(const f32x4*)(x + gbase);
    f32x4 res;
#pragma unroll
    for (int q = 0; q < 4; ++q) res[q] = gm * ov[q] + xv[q];
    *(f32x4*)(out + gbase) = res;
  }
}

// ---------------- launch ----------------
extern "C" void kernel_launch(void* const* d_in, const int* in_sizes, int n_in,
                              void* d_out, int out_size, void* d_ws, size_t ws_size,
                              hipStream_t stream) {
  const float* x     = (const float*)d_in[0];
  const float* Wq    = (const float*)d_in[1];
  const float* bq    = (const float*)d_in[2];
  const float* Wk    = (const float*)d_in[3];
  const float* bk    = (const float*)d_in[4];
  const float* Wv    = (const float*)d_in[5];
  const float* bv    = (const float*)d_in[6];
  const float* gamma = (const float*)d_in[7];
  float* out = (float*)d_out;
  (void)in_sizes; (void)n_in; (void)out_size; (void)ws_size;

  char* ws = (char*)d_ws;
  size_t off = 0;
  auto carve = [&](size_t bytes) -> char* {
    char* p = ws + off;
    off += (bytes + 255) & ~(size_t)255;
    return p;
  };
  unsigned short* xthi = (unsigned short*)carve((size_t)B_ * N_ * C_ * 2);
  unsigned short* xtlo = (unsigned short*)carve((size_t)B_ * N_ * C_ * 2);
  unsigned short* wqh  = (unsigned short*)carve(32 * 256 * 2);
  unsigned short* wql  = (unsigned short*)carve(32 * 256 * 2);
  unsigned short* wkh  = (unsigned short*)carve(32 * 256 * 2);
  unsigned short* wkl  = (unsigned short*)carve(32 * 256 * 2);
  unsigned short* wvh  = (unsigned short*)carve(256 * 256 * 2);
  unsigned short* wvl  = (unsigned short*)carve(256 * 256 * 2);
  unsigned short* qhg  = (unsigned short*)carve((size_t)B_ * N_ * CQK * 2);
  unsigned short* qlg  = (unsigned short*)carve((size_t)B_ * N_ * CQK * 2);
  unsigned short* khg  = (unsigned short*)carve((size_t)B_ * N_ * CQK * 2);
  unsigned short* klg  = (unsigned short*)carve((size_t)B_ * N_ * CQK * 2);
  unsigned short* vg   = (unsigned short*)carve((size_t)B_ * C_ * N_ * 2);

  k_split_x<<<dim3(64, 4, B_), 256, 0, stream>>>(x, xthi, xtlo);
  k_split_w<<<32, 256, 0, stream>>>(Wq, wqh, wql, 32 * 256);
  k_split_w<<<32, 256, 0, stream>>>(Wk, wkh, wkl, 32 * 256);
  k_split_w<<<256, 256, 0, stream>>>(Wv, wvh, wvl, 256 * 256);
  k_proj<<<dim3(64, 5, B_), 256, 0, stream>>>(wqh, wql, wkh, wkl, wvh, wvl,
                                              xthi, xtlo, bq, bk, bv,
                                              qhg, qlg, khg, klg, vg);
  k_flash<<<256, 512, 0, stream>>>(qhg, qlg, khg, klg, vg, x, gamma, out);
}

// Round 3
// 213.712 us; speedup vs baseline: 1.1061x; 1.1061x over previous
//
#include <hip/hip_runtime.h>

// SelfAttention (B=4, C=256, H=W=64): fused projections + split-K flash attention.
// Round 3: r2 measured k_flash=140us @ 22% occupancy (grid 256 = 1 block/CU,
// barrier-serialized, LDS-pipe-bound). Fix: split-K x2 (512 blocks, 2/CU) with
// f16 unnormalized-O partials + (m,l) stats, merged by a combine kernel that
// also applies gamma*O + x. Also merged the 4 prep launches into one k_prep.

#define B_ 4
#define C_ 256
#define N_ 4096
#define CQK 32

typedef __attribute__((ext_vector_type(8))) short short8;
typedef __attribute__((ext_vector_type(4))) short short4v;
typedef __attribute__((ext_vector_type(16))) float f32x16;
typedef __attribute__((ext_vector_type(4))) float f32x4;

__device__ __forceinline__ unsigned short f2bf(float f) {
  unsigned int u = __builtin_bit_cast(unsigned int, f);
  u = (u + 0x7fffu + ((u >> 16) & 1u)) >> 16;  // RNE
  return (unsigned short)u;
}
__device__ __forceinline__ float bf2f(unsigned short s) {
  unsigned int u = ((unsigned int)s) << 16;
  return __builtin_bit_cast(float, u);
}
__device__ __forceinline__ f32x16 mfma16(short8 a, short8 b, f32x16 c) {
  return __builtin_amdgcn_mfma_f32_32x32x16_bf16(a, b, c, 0, 0, 0);
}
// swizzled element index into bf16 LDS tiles (16B granules XORed by row)
__device__ __forceinline__ int swz64(int row, int col) {  // rows of 64 bf16
  return row * 64 + ((((col >> 3) ^ row) & 7) << 3) + (col & 7);
}
__device__ __forceinline__ int swz32(int row, int col) {  // rows of 32 bf16
  return row * 32 + ((((col >> 3) ^ row) & 3) << 3) + (col & 7);
}

// ---------------- kernel 1: prep (x transpose+split, weight splits) ----------
// blocks [0,1024): x [B][C][N] fp32 -> xthi/xtlo [B][N][C] bf16 (64x64 tiles)
// blocks [1024,1344): hi/lo split of Wq|Wk|Wv (81920 elems)
__global__ __launch_bounds__(256) void k_prep(
    const float* __restrict__ x, unsigned short* __restrict__ xthi,
    unsigned short* __restrict__ xtlo,
    const float* __restrict__ Wq, const float* __restrict__ Wk,
    const float* __restrict__ Wv,
    unsigned short* __restrict__ wqh, unsigned short* __restrict__ wql,
    unsigned short* __restrict__ wkh, unsigned short* __restrict__ wkl,
    unsigned short* __restrict__ wvh, unsigned short* __restrict__ wvl) {
  __shared__ __align__(16) float tile[64 * 65];
  const int bi = blockIdx.x;
  const int t = threadIdx.x;
  if (bi < 1024) {
    const int it = bi & 63, ct = (bi >> 6) & 3, b = bi >> 8;
    const int i0 = it * 64, c0 = ct * 64;
    {
      const int i = t & 63, cb = t >> 6;
#pragma unroll
      for (int z = 0; z < 16; ++z) {
        const int c = z * 4 + cb;
        tile[i * 65 + c] = x[(b * C_ + c0 + c) * N_ + i0 + i];
      }
    }
    __syncthreads();
    {
      const int ii = t >> 2, p = t & 3;
      short8 h0, h1, l0, l1;
#pragma unroll
      for (int e = 0; e < 16; ++e) {
        const float f = tile[ii * 65 + p * 16 + e];
        const unsigned short hb = f2bf(f);
        const unsigned short lb = f2bf(f - bf2f(hb));
        if (e < 8) { h0[e] = (short)hb; l0[e] = (short)lb; }
        else       { h1[e - 8] = (short)hb; l1[e - 8] = (short)lb; }
      }
      const int base = (b * N_ + i0 + ii) * C_ + c0 + p * 16;
      *(short8*)(xthi + base) = h0;
      *(short8*)(xthi + base + 8) = h1;
      *(short8*)(xtlo + base) = l0;
      *(short8*)(xtlo + base + 8) = l1;
    }
  } else {
    const int e = (bi - 1024) * 256 + t;  // < 81920
    const float* src; unsigned short *hi, *lo; int idx;
    if (e < 8192)        { src = Wq; hi = wqh; lo = wql; idx = e; }
    else if (e < 16384)  { src = Wk; hi = wkh; lo = wkl; idx = e - 8192; }
    else                 { src = Wv; hi = wvh; lo = wvl; idx = e - 16384; }
    const float f = src[idx];
    const unsigned short h = f2bf(f);
    hi[idx] = h;
    lo[idx] = f2bf(f - bf2f(h));
  }
}

// ---------------- kernel 2: fused q/k/v projection GEMM ----------------
// C[o][i] = sum_c W[o][c] * x[c][i] + bias, o in [0,320) concat(q32,k32,v256)
// q,k written transposed: [B][N][32] hi/lo bf16; v written [B][C][N] bf16.
__global__ __launch_bounds__(256) void k_proj(
    const unsigned short* __restrict__ wqh, const unsigned short* __restrict__ wql,
    const unsigned short* __restrict__ wkh, const unsigned short* __restrict__ wkl,
    const unsigned short* __restrict__ wvh, const unsigned short* __restrict__ wvl,
    const unsigned short* __restrict__ xthi, const unsigned short* __restrict__ xtlo,
    const float* __restrict__ bq, const float* __restrict__ bk,
    const float* __restrict__ bv,
    unsigned short* __restrict__ qhg, unsigned short* __restrict__ qlg,
    unsigned short* __restrict__ khg, unsigned short* __restrict__ klg,
    unsigned short* __restrict__ vg) {
  __shared__ __align__(16) char sm[33792];
  unsigned short* awh = (unsigned short*)sm;       // [64][64] W hi (swizzled)
  unsigned short* awl = awh + 4096;
  unsigned short* bxh = awl + 4096;                // [64][64] x^T hi
  unsigned short* bxl = bxh + 4096;
  float* qt = (float*)sm;                          // epilogue reuse: [64][65] f32

  const int it = blockIdx.x, ot = blockIdx.y, b = blockIdx.z;
  const int i0 = it * 64, o0 = ot * 64;
  const int t = threadIdx.x, lane = t & 63, w = t >> 6, h = lane >> 5;
  const int mb = w >> 1, nb = w & 1;
  const int srow = t >> 2, sp = t & 3;

  const int og = o0 + srow;
  const unsigned short *wh, *wl;
  if (og < 32)      { wh = wqh + og * C_;        wl = wql + og * C_; }
  else if (og < 64) { wh = wkh + (og - 32) * C_; wl = wkl + (og - 32) * C_; }
  else              { wh = wvh + (og - 64) * C_; wl = wvl + (og - 64) * C_; }
  const unsigned short* xh = xthi + (b * N_ + i0 + srow) * C_;
  const unsigned short* xl = xtlo + (b * N_ + i0 + srow) * C_;

  f32x16 acc;
#pragma unroll
  for (int e = 0; e < 16; ++e) acc[e] = 0.f;
  const int m = 32 * mb + (lane & 31);
  const int n = 32 * nb + (lane & 31);

  for (int kt = 0; kt < 4; ++kt) {
    const int cb = kt * 64 + sp * 16;
    *(short8*)&awh[swz64(srow, sp * 16)]     = *(const short8*)(wh + cb);
    *(short8*)&awh[swz64(srow, sp * 16 + 8)] = *(const short8*)(wh + cb + 8);
    *(short8*)&awl[swz64(srow, sp * 16)]     = *(const short8*)(wl + cb);
    *(short8*)&awl[swz64(srow, sp * 16 + 8)] = *(const short8*)(wl + cb + 8);
    *(short8*)&bxh[swz64(srow, sp * 16)]     = *(const short8*)(xh + cb);
    *(short8*)&bxh[swz64(srow, sp * 16 + 8)] = *(const short8*)(xh + cb + 8);
    *(short8*)&bxl[swz64(srow, sp * 16)]     = *(const short8*)(xl + cb);
    *(short8*)&bxl[swz64(srow, sp * 16 + 8)] = *(const short8*)(xl + cb + 8);
    __syncthreads();
#pragma unroll
    for (int kk = 0; kk < 4; ++kk) {
      const int kb = kk * 16 + h * 8;
      const short8 ah  = *(const short8*)&awh[swz64(m, kb)];
      const short8 al2 = *(const short8*)&awl[swz64(m, kb)];
      const short8 bh  = *(const short8*)&bxh[swz64(n, kb)];
      const short8 bl2 = *(const short8*)&bxl[swz64(n, kb)];
      acc = mfma16(ah, bh, acc);   // hi*hi
      acc = mfma16(ah, bl2, acc);  // hi*lo
      acc = mfma16(al2, bh, acc);  // lo*hi
    }
    __syncthreads();
  }

  if (ot > 0) {  // v epilogue: direct [B][C][N] bf16 store
#pragma unroll
    for (int e = 0; e < 16; ++e) {
      const int r = 32 * mb + (e & 3) + 8 * (e >> 2) + 4 * h;
      const int oc = o0 - 64 + r;
      vg[(b * C_ + oc) * N_ + i0 + n] = f2bf(acc[e] + bv[oc]);
    }
  } else {  // q/k epilogue: LDS transpose -> [B][N][32] hi/lo
#pragma unroll
    for (int e = 0; e < 16; ++e) {
      const int r = 32 * mb + (e & 3) + 8 * (e >> 2) + 4 * h;
      const float bias = (r < 32) ? bq[r] : bk[r - 32];
      qt[r * 65 + n] = acc[e] + bias;
    }
    __syncthreads();
    const int ii = t >> 2;
    short8 hv0, hv1, lv0, lv1;
#pragma unroll
    for (int e = 0; e < 16; ++e) {
      const float f = qt[(sp * 16 + e) * 65 + ii];
      const unsigned short hb = f2bf(f);
      const unsigned short lb = f2bf(f - bf2f(hb));
      if (e < 8) { hv0[e] = (short)hb; lv0[e] = (short)lb; }
      else       { hv1[e - 8] = (short)hb; lv1[e - 8] = (short)lb; }
    }
    if (sp < 2) {
      const int base = (b * N_ + i0 + ii) * CQK + sp * 16;
      *(short8*)(qhg + base) = hv0; *(short8*)(qhg + base + 8) = hv1;
      *(short8*)(qlg + base) = lv0; *(short8*)(qlg + base + 8) = lv1;
    } else {
      const int base = (b * N_ + i0 + ii) * CQK + sp * 16 - 32;
      *(short8*)(khg + base) = hv0; *(short8*)(khg + base + 8) = hv1;
      *(short8*)(klg + base) = lv0; *(short8*)(klg + base + 8) = lv1;
    }
  }
}

// ---------------- kernel 3: split-K flash attention ----------------
// 512 blocks: blk = (qt<<3)|(b<<1)|half. Each block: Qtile=64, keys
// [half*2048, half*2048+2048) in 32 iters of 64. Writes unnormalized O (f16,
// [c][i] layout) + per-row (m,l) stats for the combine kernel.
__global__ __launch_bounds__(512, 4) void k_flash(
    const unsigned short* __restrict__ qhg, const unsigned short* __restrict__ qlg,
    const unsigned short* __restrict__ khg, const unsigned short* __restrict__ klg,
    const unsigned short* __restrict__ vg,
    unsigned short* __restrict__ Opart, float* __restrict__ mlpart) {
  __shared__ __align__(16) char sm[65536];
  unsigned short* kh = (unsigned short*)sm;           // [64][32] (Q-hi staging first)
  unsigned short* kl = (unsigned short*)(sm + 4096);  // [64][32] (Q-lo staging first)
  unsigned short* vt = (unsigned short*)(sm + 8192);  // [256][64]
  float* stf = (float*)(sm + 40960);                  // [64][64] f32 swizzled; P aliases
  char* stb = sm + 40960;
  float* alphaf = (float*)(sm + 57344);               // [64]
  float* otf = (float*)sm;                            // epilogue [256][64] swizzled

  // XCD-aware: blk%8 = XCD -> fixed (b,half) per XCD; per-XCD K/V ~1.3MB < L2.
  const int blk = blockIdx.x;
  const int b = (blk >> 1) & 3;
  const int half = blk & 1;
  const int qt_ = blk >> 3;
  const int q0 = qt_ * 64;
  const int jbase = half * 2048;
  const int t = threadIdx.x, lane = t & 63, w = t >> 6, h = lane >> 5;
  const int l31 = lane & 31;
  const int r_sm = t >> 3, p_sm = t & 7;

  // stage Q tile (hi into kh region, lo into kl region)
  {
    const int r = (t & 255) >> 2, g = t & 3;
    const unsigned short* src = ((t < 256) ? qhg : qlg) + (b * N_ + q0 + r) * CQK + g * 8;
    unsigned short* dst = (t < 256) ? kh : kl;
    *(short8*)&dst[swz32(r, g * 8)] = *(const short8*)src;
  }
  __syncthreads();
  // preload Q fragments (used by waves 0..3 for S)
  const int mbs = (w >> 1) & 1, nbs = w & 1;
  short8 qfh[2], qfl[2];
  {
    const int mq = 32 * mbs + l31;
#pragma unroll
    for (int kk = 0; kk < 2; ++kk) {
      qfh[kk] = *(const short8*)&kh[swz32(mq, kk * 16 + h * 8)];
      qfl[kk] = *(const short8*)&kl[swz32(mq, kk * 16 + h * 8)];
    }
  }
  __syncthreads();  // Q region becomes K staging below

  f32x16 acc0, acc1;
#pragma unroll
  for (int e = 0; e < 16; ++e) { acc0[e] = 0.f; acc1[e] = 0.f; }
  float m_run = -1e30f, l_run = 0.f;

  for (int kt = 0; kt < 32; ++kt) {
    const int j0 = jbase + kt * 64;
    {  // stage K hi/lo
      const int r = (t & 255) >> 2, g = t & 3;
      const unsigned short* src = ((t < 256) ? khg : klg) + (b * N_ + j0 + r) * CQK + g * 8;
      unsigned short* dst = (t < 256) ? kh : kl;
      *(short8*)&dst[swz32(r, g * 8)] = *(const short8*)src;
    }
#pragma unroll
    for (int pass = 0; pass < 4; ++pass) {  // stage V [256][64]
      const int gid = pass * 512 + t;
      const int c = gid >> 3, g = gid & 7;
      *(short8*)&vt[swz64(c, g * 8)] =
          *(const short8*)(vg + (b * C_ + c) * N_ + j0 + g * 8);
    }
    __syncthreads();
    // S = Q K^T (waves 0..3), fp32, written swizzled to stf
    if (w < 4) {
      f32x16 sa;
#pragma unroll
      for (int e = 0; e < 16; ++e) sa[e] = 0.f;
      const int jn = 32 * nbs + l31;
#pragma unroll
      for (int kk = 0; kk < 2; ++kk) {
        const short8 bh = *(const short8*)&kh[swz32(jn, kk * 16 + h * 8)];
        const short8 bl = *(const short8*)&kl[swz32(jn, kk * 16 + h * 8)];
        sa = mfma16(qfh[kk], bh, sa);
        sa = mfma16(qfh[kk], bl, sa);
        sa = mfma16(qfl[kk], bh, sa);
      }
#pragma unroll
      for (int e = 0; e < 16; ++e) {
        const int ri = 32 * mbs + (e & 3) + 8 * (e >> 2) + 4 * h;
        stf[ri * 64 + ((((jn >> 2) ^ ri) & 15) << 2) + (jn & 3)] = sa[e];
      }
    }
    __syncthreads();
    // online softmax: thread (r_sm,p_sm) owns cols [8p,8p+8) of row r_sm
    {
      float* p0 = stf + r_sm * 64 + ((((2 * p_sm) ^ r_sm) & 15) << 2);
      float* p1 = stf + r_sm * 64 + ((((2 * p_sm + 1) ^ r_sm) & 15) << 2);
      const f32x4 a0 = *(const f32x4*)p0;
      const f32x4 a1 = *(const f32x4*)p1;
      float s[8];
#pragma unroll
      for (int e = 0; e < 4; ++e) { s[e] = a0[e]; s[4 + e] = a1[e]; }
      float mx = s[0];
#pragma unroll
      for (int e = 1; e < 8; ++e) mx = fmaxf(mx, s[e]);
      mx = fmaxf(mx, __shfl_xor(mx, 1));
      mx = fmaxf(mx, __shfl_xor(mx, 2));
      mx = fmaxf(mx, __shfl_xor(mx, 4));
      const float mnew = fmaxf(m_run, mx);
      const float al = __expf(m_run - mnew);
      float ts = 0.f;
      short8 pv8;
#pragma unroll
      for (int e = 0; e < 8; ++e) {
        const float pe = __expf(s[e] - mnew);
        ts += pe;
        pv8[e] = (short)f2bf(pe);
      }
      ts += __shfl_xor(ts, 1);
      ts += __shfl_xor(ts, 2);
      ts += __shfl_xor(ts, 4);
      l_run = l_run * al + ts;
      m_run = mnew;
      *(short8*)p0 = pv8;  // P (bf16) overwrites the granule this thread read
      if (p_sm == 0) alphaf[r_sm] = al;
    }
    __syncthreads();
    // rescale O by alpha[row]
#pragma unroll
    for (int eq = 0; eq < 4; ++eq) {
      const f32x4 av0 = *(const f32x4*)&alphaf[4 * h + 8 * eq];
      const f32x4 av1 = *(const f32x4*)&alphaf[32 + 4 * h + 8 * eq];
#pragma unroll
      for (int q = 0; q < 4; ++q) {
        acc0[4 * eq + q] *= av0[q];
        acc1[4 * eq + q] *= av1[q];
      }
    }
    // O += P * V^T
    {
      const int crow = 32 * w + l31;
#pragma unroll
      for (int kk = 0; kk < 4; ++kk) {
        const int g0 = ((4 * kk + 2 * h) ^ l31) & 15;  // P col-granule swizzle
        const short8 pa0 = *(const short8*)(stb + l31 * 256 + (g0 << 4));
        const short8 pa1 = *(const short8*)(stb + (32 + l31) * 256 + (g0 << 4));
        const short8 vf = *(const short8*)&vt[swz64(crow, kk * 16 + h * 8)];
        acc0 = mfma16(pa0, vf, acc0);
        acc1 = mfma16(pa1, vf, acc1);
      }
    }
    __syncthreads();
  }

  // write per-row stats (m,l); O stays unnormalized (combine divides)
  if (p_sm == 0) {
    mlpart[blk * 128 + r_sm] = m_run;
    mlpart[blk * 128 + 64 + r_sm] = l_run;
  }
  // transpose O through LDS, store f16 partials [c][i]
  {
    const int cc = 32 * w + l31;
#pragma unroll
    for (int e = 0; e < 16; ++e) {
      const int r0 = (e & 3) + 8 * (e >> 2) + 4 * h;
      otf[cc * 64 + ((((r0 >> 2) ^ cc) & 15) << 2) + (r0 & 3)] = acc0[e];
      const int r1 = 32 + r0;
      otf[cc * 64 + ((((r1 >> 2) ^ cc) & 15) << 2) + (r1 & 3)] = acc1[e];
    }
  }
  __syncthreads();
#pragma unroll
  for (int pass = 0; pass < 8; ++pass) {
    const int idx = pass * 512 + t;
    const int c = idx >> 4, gi = idx & 15;
    const f32x4 ov = *(const f32x4*)(otf + c * 64 + (((gi ^ c) & 15) << 2));
    short4v hv;
#pragma unroll
    for (int q = 0; q < 4; ++q) {
      const _Float16 hf = (_Float16)ov[q];
      hv[q] = __builtin_bit_cast(short, hf);
    }
    *(short4v*)(Opart + blk * 16384 + c * 64 + gi * 4) = hv;
  }
}

// ---------------- kernel 4: combine halves + residual ----------------
// grid 256 = (b,qt). O = (w1*O1u + w2*O2u) / (w1*l1 + w2*l2); out = g*O + x.
__global__ __launch_bounds__(256) void k_combine(
    const unsigned short* __restrict__ Opart, const float* __restrict__ mlpart,
    const float* __restrict__ x, const float* __restrict__ gamma,
    float* __restrict__ out) {
  const int cb = blockIdx.x;
  const int b = cb & 3, qt_ = cb >> 2;
  const int q0 = qt_ * 64;
  const int blk1 = (qt_ << 3) | (b << 1);
  const int blk2 = blk1 | 1;
  const int t = threadIdx.x;
  const int i = t & 63, cg = t >> 6;

  const float m1 = mlpart[blk1 * 128 + i], l1 = mlpart[blk1 * 128 + 64 + i];
  const float m2 = mlpart[blk2 * 128 + i], l2 = mlpart[blk2 * 128 + 64 + i];
  const float M = fmaxf(m1, m2);
  const float w1 = __expf(m1 - M), w2 = __expf(m2 - M);
  const float inv = 1.f / (w1 * l1 + w2 * l2);
  const float gm = gamma[0];
  const float s1 = gm * w1 * inv, s2 = gm * w2 * inv;

  const unsigned short* p1 = Opart + blk1 * 16384 + i;
  const unsigned short* p2 = Opart + blk2 * 16384 + i;
#pragma unroll 4
  for (int c = cg; c < C_; c += 4) {
    const float o1 = (float)__builtin_bit_cast(_Float16, p1[c * 64]);
    const float o2 = (float)__builtin_bit_cast(_Float16, p2[c * 64]);
    const int g = (b * C_ + c) * N_ + q0 + i;
    out[g] = s1 * o1 + s2 * o2 + x[g];
  }
}

// ---------------- launch ----------------
extern "C" void kernel_launch(void* const* d_in, const int* in_sizes, int n_in,
                              void* d_out, int out_size, void* d_ws, size_t ws_size,
                              hipStream_t stream) {
  const float* x     = (const float*)d_in[0];
  const float* Wq    = (const float*)d_in[1];
  const float* bq    = (const float*)d_in[2];
  const float* Wk    = (const float*)d_in[3];
  const float* bk    = (const float*)d_in[4];
  const float* Wv    = (const float*)d_in[5];
  const float* bv    = (const float*)d_in[6];
  const float* gamma = (const float*)d_in[7];
  float* out = (float*)d_out;
  (void)in_sizes; (void)n_in; (void)out_size; (void)ws_size;

  char* ws = (char*)d_ws;
  size_t off = 0;
  auto carve = [&](size_t bytes) -> char* {
    char* p = ws + off;
    off += (bytes + 255) & ~(size_t)255;
    return p;
  };
  unsigned short* xthi = (unsigned short*)carve((size_t)B_ * N_ * C_ * 2);
  unsigned short* xtlo = (unsigned short*)carve((size_t)B_ * N_ * C_ * 2);
  unsigned short* wqh  = (unsigned short*)carve(32 * 256 * 2);
  unsigned short* wql  = (unsigned short*)carve(32 * 256 * 2);
  unsigned short* wkh  = (unsigned short*)carve(32 * 256 * 2);
  unsigned short* wkl  = (unsigned short*)carve(32 * 256 * 2);
  unsigned short* wvh  = (unsigned short*)carve(256 * 256 * 2);
  unsigned short* wvl  = (unsigned short*)carve(256 * 256 * 2);
  unsigned short* qhg  = (unsigned short*)carve((size_t)B_ * N_ * CQK * 2);
  unsigned short* qlg  = (unsigned short*)carve((size_t)B_ * N_ * CQK * 2);
  unsigned short* khg  = (unsigned short*)carve((size_t)B_ * N_ * CQK * 2);
  unsigned short* klg  = (unsigned short*)carve((size_t)B_ * N_ * CQK * 2);
  unsigned short* vg   = (unsigned short*)carve((size_t)B_ * C_ * N_ * 2);
  unsigned short* Opart = (unsigned short*)carve((size_t)512 * 16384 * 2);  // f16
  float* mlpart = (float*)carve((size_t)512 * 128 * 4);

  k_prep<<<1344, 256, 0, stream>>>(x, xthi, xtlo, Wq, Wk, Wv,
                                   wqh, wql, wkh, wkl, wvh, wvl);
  k_proj<<<dim3(64, 5, B_), 256, 0, stream>>>(wqh, wql, wkh, wkl, wvh, wvl,
                                              xthi, xtlo, bq, bk, bv,
                                              qhg, qlg, khg, klg, vg);
  k_flash<<<512, 512, 0, stream>>>(qhg, qlg, khg, klg, vg, Opart, mlpart);
  k_combine<<<256, 256, 0, stream>>>(Opart, mlpart, x, gamma, out);
}